// Round 5
// baseline (94.448 us; speedup 1.0000x reference)
//
#include <hip/hip_runtime.h>

#define B_N 8
#define A_N 100000
#define M_N 64
#define ANCH 4
#define TPB 256
#define GX ((A_N + TPB * ANCH - 1) / (TPB * ANCH))   // 98 blocks per batch
#define NBLK (GX * B_N)                              // 784 total

// d_ws layout: ws_num[B_N], ws_cnt[B_N], ticket (uint). 68 bytes zeroed
// per call via hipMemsetAsync (graph-capturable).

__global__ __launch_bounds__(TPB) void rl_fused(
    const float* __restrict__ regressions,   // (B, A, 2)
    const float* __restrict__ anchors,       // (1, A, 2)
    const float* __restrict__ annotations,   // (B, M, 3)
    float* __restrict__ ws_num, float* __restrict__ ws_cnt,
    unsigned int* __restrict__ ticket,
    float* __restrict__ out)
{
    __shared__ float4 ann[M_N];              // {x1, x2, len, 0}
    const int b = blockIdx.y;
    const int tid = threadIdx.x;

    if (tid < M_N) {
        const float* p = annotations + (b * M_N + tid) * 3;
        float x1 = p[0], x2 = p[1], lab = p[2];
        if (lab == -1.0f) { x1 = 1e30f; x2 = 1e30f; }
        // invalid => iw hugely negative, len=0 => can only "win" while no
        // positive overlap exists, and then the 0.5 gate fails anyway.
        ann[tid] = make_float4(x1, x2, x2 - x1, 0.0f);
    }
    __syncthreads();

    const int abase = blockIdx.x * (TPB * ANCH) + tid;

    float a0[ANCH], a1[ANCH], aw[ANCH];
    float iwb0[ANCH], Sb0[ANCH], iwb1[ANCH], Sb1[ANCH];
    int idx0[ANCH], idx1[ANCH];
    bool act[ANCH];
    #pragma unroll
    for (int k = 0; k < ANCH; ++k) {
        int a = abase + k * TPB;
        act[k] = (a < A_N);
        a = act[k] ? a : (A_N - 1);
        const float2 anc = ((const float2*)anchors)[a];
        a0[k] = anc.x; a1[k] = anc.y; aw[k] = anc.y - anc.x;
        iwb0[k] = -1.0f; Sb0[k] = 1.0f; idx0[k] = 0;   // encodes iou = -1
        iwb1[k] = -1.0f; Sb1[k] = 1.0f; idx1[k] = 32;
    }

    // 8 chains/thread (4 anchors x 2 m-halves), pair tournament per half.
    // iou = iw/(S-iw), S = aw+len: monotone in iw/S -> cross-mul compare.
    #pragma unroll 4
    for (int p = 0; p < M_N / 4; ++p) {
        const int m = 2 * p;
        const float4 t0 = ann[m];
        const float4 t1 = ann[m + 1];
        const float4 u0 = ann[m + 32];
        const float4 u1 = ann[m + 33];
        #pragma unroll
        for (int k = 0; k < ANCH; ++k) {
            {
                const float iw0 = fminf(a1[k], t0.y) - fmaxf(a0[k], t0.x);
                const float iw1 = fminf(a1[k], t1.y) - fmaxf(a0[k], t1.x);
                const float S0 = aw[k] + t0.z;
                const float S1 = aw[k] + t1.z;
                const bool w1 = iw1 * S0 > iw0 * S1;          // tie -> m
                const float iww = w1 ? iw1 : iw0;
                const float Sw  = w1 ? S1  : S0;
                const int   mw  = w1 ? m + 1 : m;
                const bool bet = iww * Sb0[k] > iwb0[k] * Sw; // tie -> best
                iwb0[k] = bet ? iww : iwb0[k];
                Sb0[k]  = bet ? Sw  : Sb0[k];
                idx0[k] = bet ? mw  : idx0[k];
            }
            {
                const float iw0 = fminf(a1[k], u0.y) - fmaxf(a0[k], u0.x);
                const float iw1 = fminf(a1[k], u1.y) - fmaxf(a0[k], u1.x);
                const float S0 = aw[k] + u0.z;
                const float S1 = aw[k] + u1.z;
                const bool w1 = iw1 * S0 > iw0 * S1;
                const float iww = w1 ? iw1 : iw0;
                const float Sw  = w1 ? S1  : S0;
                const int   mw  = w1 ? m + 33 : m + 32;
                const bool bet = iww * Sb1[k] > iwb1[k] * Sw;
                iwb1[k] = bet ? iww : iwb1[k];
                Sb1[k]  = bet ? Sw  : Sb1[k];
                idx1[k] = bet ? mw  : idx1[k];
            }
        }
    }

    float lsum = 0.0f, lpos = 0.0f;
    #pragma unroll
    for (int k = 0; k < ANCH; ++k) {
        // merge halves: strict '>' keeps half-0 (lower index) on ties
        const bool h1 = iwb1[k] * Sb0[k] > iwb0[k] * Sb1[k];
        const float iwb = h1 ? iwb1[k] : iwb0[k];
        const float Sb  = h1 ? Sb1[k]  : Sb0[k];
        const int   idx = h1 ? idx1[k] : idx0[k];
        // exact gate, reference rounding order
        const float ua  = fmaxf(Sb - iwb, 1e-8f);
        const float iou = iwb / ua;
        if (act[k] && iou >= 0.5f) {
            const float4 g = ann[idx];
            const float gw0 = g.z;
            const float gcx = g.x + 0.5f * gw0;
            const float gw  = fmaxf(gw0, 1.0f);
            const float acx = a0[k] + 0.5f * aw[k];
            const float tdx = ((gcx - acx) / aw[k]) / 0.1f;
            const float tdw = logf(gw / aw[k]) / 0.2f;
            const float2 rg =
                ((const float2*)regressions)[(size_t)b * A_N + abase + k * TPB];
            const float d0 = fabsf(tdx - rg.x);
            const float d1 = fabsf(tdw - rg.y);
            const float inv9 = 1.0f / 9.0f;
            const float s0 = (d0 <= inv9) ? 4.5f * d0 * d0 : d0 - 0.5f / 9.0f;
            const float s1 = (d1 <= inv9) ? 4.5f * d1 * d1 : d1 - 0.5f / 9.0f;
            lsum += s0 + s1;
            lpos += 1.0f;
        }
    }

    for (int o = 32; o > 0; o >>= 1) {
        lsum += __shfl_down(lsum, o, 64);
        lpos += __shfl_down(lpos, o, 64);
    }
    __shared__ float wsum[TPB / 64], wpos[TPB / 64];
    const int wid  = tid >> 6;
    const int lane = tid & 63;
    if (lane == 0) { wsum[wid] = lsum; wpos[wid] = lpos; }
    __syncthreads();

    if (tid == 0) {
        float s = 0.0f, p = 0.0f;
        #pragma unroll
        for (int w = 0; w < TPB / 64; ++w) { s += wsum[w]; p += wpos[w]; }
        atomicAdd(&ws_num[b], s);        // device-scope by default
        atomicAdd(&ws_cnt[b], p);
        // release: orders the two atomicAdds before the ticket increment;
        // the last block's acquire on the same ticket makes ALL partials
        // visible to it. Dispatch-order-independent.
        const unsigned int old = __hip_atomic_fetch_add(
            ticket, 1u, __ATOMIC_ACQ_REL, __HIP_MEMORY_SCOPE_AGENT);
        if (old == NBLK - 1) {
            float acc = 0.0f;
            #pragma unroll
            for (int i = 0; i < B_N; ++i) {
                const float sn = __hip_atomic_load(
                    &ws_num[i], __ATOMIC_RELAXED, __HIP_MEMORY_SCOPE_AGENT);
                const float sc = __hip_atomic_load(
                    &ws_cnt[i], __ATOMIC_RELAXED, __HIP_MEMORY_SCOPE_AGENT);
                const float cnt = 2.0f * sc;
                acc += (cnt > 0.0f) ? sn / fmaxf(cnt, 1.0f) : 0.0f;
            }
            out[0] = acc * (1.0f / (float)B_N);
        }
    }
}

extern "C" void kernel_launch(void* const* d_in, const int* in_sizes, int n_in,
                              void* d_out, int out_size, void* d_ws, size_t ws_size,
                              hipStream_t stream) {
    const float* regressions = (const float*)d_in[0];
    const float* anchors     = (const float*)d_in[1];
    const float* annotations = (const float*)d_in[2];
    float* out = (float*)d_out;

    float* ws_num = (float*)d_ws;                        // [B_N]
    float* ws_cnt = ws_num + B_N;                        // [B_N]
    unsigned int* ticket = (unsigned int*)(ws_cnt + B_N);

    hipMemsetAsync(d_ws, 0, (2 * B_N + 1) * sizeof(float), stream);

    dim3 grid(GX, B_N);
    rl_fused<<<grid, TPB, 0, stream>>>(regressions, anchors, annotations,
                                       ws_num, ws_cnt, ticket, out);
}

// Round 6
// 82.755 us; speedup vs baseline: 1.1413x; 1.1413x over previous
//
#include <hip/hip_runtime.h>

#define B_N 8
#define A_N 100000
#define M_N 64
#define ANCH 2
#define TPB 256
#define GX ((A_N + TPB * ANCH - 1) / (TPB * ANCH))   // 196 blocks per batch

__global__ __launch_bounds__(TPB) void rl_main(
    const float* __restrict__ regressions,   // (B, A, 2)
    const float* __restrict__ anchors,       // (1, A, 2)
    const float* __restrict__ annotations,   // (B, M, 3)
    float* __restrict__ ws_num, float* __restrict__ ws_cnt)
{
    __shared__ float4 ann[M_N];              // {x1, x2, len, 0} epilogue use
    const int b = blockIdx.y;
    const int tid = threadIdx.x;

    if (tid < M_N) {
        const float* p = annotations + (b * M_N + tid) * 3;
        float x1 = p[0], x2 = p[1], lab = p[2];
        if (lab == -1.0f) { x1 = 1e30f; x2 = 1e30f; }
        // invalid => iw hugely negative, len=0 => can only "win" while no
        // real overlap exists, and then the 0.5 gate fails anyway.
        ann[tid] = make_float4(x1, x2, x2 - x1, 0.0f);
    }
    // no sync yet: hot loop reads annotations via wave-uniform global
    // (scalar) loads; LDS copy is only needed at the epilogue.

    const int abase = blockIdx.x * (TPB * ANCH) + tid;

    float a0[ANCH], a1[ANCH], aw[ANCH];
    float iwb0[ANCH], Sb0[ANCH], iwb1[ANCH], Sb1[ANCH];
    int idx0[ANCH], idx1[ANCH];
    bool act[ANCH];
    #pragma unroll
    for (int k = 0; k < ANCH; ++k) {
        int a = abase + k * TPB;
        act[k] = (a < A_N);
        a = act[k] ? a : (A_N - 1);
        const float2 anc = ((const float2*)anchors)[a];
        a0[k] = anc.x; a1[k] = anc.y; aw[k] = anc.y - anc.x;
        iwb0[k] = -1.0f; Sb0[k] = 1.0f; idx0[k] = 0;   // encodes iou = -1
        iwb1[k] = -1.0f; Sb1[k] = 1.0f; idx1[k] = 32;
    }

    // 4 chains/thread (2 anchors x 2 m-halves), pair tournament per half.
    // iou = iw/(S-iw), S = aw+len: monotone in iw/S -> cross-mul compare.
    // Reconstruct {x1,x2,len} from global with wave-uniform addresses.
    const float* annb3 = annotations + b * M_N * 3;
    #pragma unroll 4
    for (int p = 0; p < M_N / 4; ++p) {
        const int m = 2 * p;
        // load 2+2 annotations (raw {x1,x2,lab}); recompute transform
        const float t0x1r = annb3[3 * m + 0],  t0x2r = annb3[3 * m + 1],  t0l = annb3[3 * m + 2];
        const float t1x1r = annb3[3 * m + 3],  t1x2r = annb3[3 * m + 4],  t1l = annb3[3 * m + 5];
        const float u0x1r = annb3[3 * (m + 32) + 0], u0x2r = annb3[3 * (m + 32) + 1], u0l = annb3[3 * (m + 32) + 2];
        const float u1x1r = annb3[3 * (m + 32) + 3], u1x2r = annb3[3 * (m + 32) + 4], u1l = annb3[3 * (m + 32) + 5];
        const bool t0v = (t0l != -1.0f), t1v = (t1l != -1.0f);
        const bool u0v = (u0l != -1.0f), u1v = (u1l != -1.0f);
        const float t0x1 = t0v ? t0x1r : 1e30f, t0x2 = t0v ? t0x2r : 1e30f;
        const float t1x1 = t1v ? t1x1r : 1e30f, t1x2 = t1v ? t1x2r : 1e30f;
        const float u0x1 = u0v ? u0x1r : 1e30f, u0x2 = u0v ? u0x2r : 1e30f;
        const float u1x1 = u1v ? u1x1r : 1e30f, u1x2 = u1v ? u1x2r : 1e30f;
        const float t0z = t0x2 - t0x1, t1z = t1x2 - t1x1;
        const float u0z = u0x2 - u0x1, u1z = u1x2 - u1x1;
        #pragma unroll
        for (int k = 0; k < ANCH; ++k) {
            {
                const float iw0 = fminf(a1[k], t0x2) - fmaxf(a0[k], t0x1);
                const float iw1 = fminf(a1[k], t1x2) - fmaxf(a0[k], t1x1);
                const float S0 = aw[k] + t0z;
                const float S1 = aw[k] + t1z;
                const bool w1 = iw1 * S0 > iw0 * S1;          // tie -> m
                const float iww = w1 ? iw1 : iw0;
                const float Sw  = w1 ? S1  : S0;
                const int   mw  = w1 ? m + 1 : m;
                const bool bet = iww * Sb0[k] > iwb0[k] * Sw; // tie -> best
                iwb0[k] = bet ? iww : iwb0[k];
                Sb0[k]  = bet ? Sw  : Sb0[k];
                idx0[k] = bet ? mw  : idx0[k];
            }
            {
                const float iw0 = fminf(a1[k], u0x2) - fmaxf(a0[k], u0x1);
                const float iw1 = fminf(a1[k], u1x2) - fmaxf(a0[k], u1x1);
                const float S0 = aw[k] + u0z;
                const float S1 = aw[k] + u1z;
                const bool w1 = iw1 * S0 > iw0 * S1;
                const float iww = w1 ? iw1 : iw0;
                const float Sw  = w1 ? S1  : S0;
                const int   mw  = w1 ? m + 33 : m + 32;
                const bool bet = iww * Sb1[k] > iwb1[k] * Sw;
                iwb1[k] = bet ? iww : iwb1[k];
                Sb1[k]  = bet ? Sw  : Sb1[k];
                idx1[k] = bet ? mw  : idx1[k];
            }
        }
    }

    __syncthreads();   // ann[] ready for epilogue random access

    float lsum = 0.0f, lpos = 0.0f;
    #pragma unroll
    for (int k = 0; k < ANCH; ++k) {
        // merge halves: strict '>' keeps half-0 (lower index) on ties
        const bool h1 = iwb1[k] * Sb0[k] > iwb0[k] * Sb1[k];
        const float iwb = h1 ? iwb1[k] : iwb0[k];
        const float Sb  = h1 ? Sb1[k]  : Sb0[k];
        const int   idx = h1 ? idx1[k] : idx0[k];
        // exact gate, reference rounding order
        const float ua  = fmaxf(Sb - iwb, 1e-8f);
        const float iou = iwb / ua;
        if (act[k] && iou >= 0.5f) {
            const float4 g = ann[idx];
            const float gw0 = g.z;
            const float gcx = g.x + 0.5f * gw0;
            const float gw  = fmaxf(gw0, 1.0f);
            const float acx = a0[k] + 0.5f * aw[k];
            const float tdx = ((gcx - acx) / aw[k]) / 0.1f;
            const float tdw = logf(gw / aw[k]) / 0.2f;
            const float2 rg =
                ((const float2*)regressions)[(size_t)b * A_N + abase + k * TPB];
            const float d0 = fabsf(tdx - rg.x);
            const float d1 = fabsf(tdw - rg.y);
            const float inv9 = 1.0f / 9.0f;
            const float s0 = (d0 <= inv9) ? 4.5f * d0 * d0 : d0 - 0.5f / 9.0f;
            const float s1 = (d1 <= inv9) ? 4.5f * d1 * d1 : d1 - 0.5f / 9.0f;
            lsum += s0 + s1;
            lpos += 1.0f;
        }
    }

    for (int o = 32; o > 0; o >>= 1) {
        lsum += __shfl_down(lsum, o, 64);
        lpos += __shfl_down(lpos, o, 64);
    }
    __shared__ float wsum[TPB / 64], wpos[TPB / 64];
    const int wid  = tid >> 6;
    const int lane = tid & 63;
    if (lane == 0) { wsum[wid] = lsum; wpos[wid] = lpos; }
    __syncthreads();
    if (tid == 0) {
        float s = 0.0f, p = 0.0f;
        #pragma unroll
        for (int w = 0; w < TPB / 64; ++w) { s += wsum[w]; p += wpos[w]; }
        const int slot = b * GX + blockIdx.x;
        ws_num[slot] = s;
        ws_cnt[slot] = p;
    }
}

__global__ __launch_bounds__(512) void rl_final(
    const float* __restrict__ ws_num,
    const float* __restrict__ ws_cnt,
    float* __restrict__ out)
{
    const int wid  = threadIdx.x >> 6;   // wave w handles batch w
    const int lane = threadIdx.x & 63;
    float s = 0.0f, c = 0.0f;
    for (int i = lane; i < GX; i += 64) {
        s += ws_num[wid * GX + i];
        c += ws_cnt[wid * GX + i];
    }
    for (int o = 32; o > 0; o >>= 1) {
        s += __shfl_down(s, o, 64);
        c += __shfl_down(c, o, 64);
    }
    __shared__ float pb[B_N];
    if (lane == 0) {
        const float cnt = 2.0f * c;
        pb[wid] = (cnt > 0.0f) ? s / fmaxf(cnt, 1.0f) : 0.0f;
    }
    __syncthreads();
    if (threadIdx.x == 0) {
        float acc = 0.0f;
        #pragma unroll
        for (int i = 0; i < B_N; ++i) acc += pb[i];
        out[0] = acc * (1.0f / (float)B_N);
    }
}

extern "C" void kernel_launch(void* const* d_in, const int* in_sizes, int n_in,
                              void* d_out, int out_size, void* d_ws, size_t ws_size,
                              hipStream_t stream) {
    const float* regressions = (const float*)d_in[0];
    const float* anchors     = (const float*)d_in[1];
    const float* annotations = (const float*)d_in[2];
    float* out = (float*)d_out;

    float* ws_num = (float*)d_ws;                 // [B_N * GX]
    float* ws_cnt = ws_num + B_N * GX;            // [B_N * GX]

    dim3 grid(GX, B_N);
    rl_main<<<grid, TPB, 0, stream>>>(regressions, anchors, annotations,
                                      ws_num, ws_cnt);
    rl_final<<<1, 512, 0, stream>>>(ws_num, ws_cnt, out);
}